// Round 1
// baseline (2430.206 us; speedup 1.0000x reference)
//
#include <hip/hip_runtime.h>

// CharNNClassifier: out = (LSTM(emb[x]) last h) @ W_out^T + b_out
// B=256 S=512 V=256 E=128 H=256 4H=1024 O=128, fp32 in/out.
//
// R4 design: hidden-split across workgroup pairs (2x CU utilization).
//  R3 (16 wgs, 1809 us) was issue-bound per active CU (MfmaUtil 25%,
//  VALUBusy 50% per-active-CU) with 94% of the chip idle, and W_hh
//  (512 KB fp16 = whole CU register file) forced a reg/LDS split + spills.
//
//  R4: 32 wgs = (stripe 0..15) x (half 0..1). Each wg owns 128 hidden
//  units (4 gates x 128 gate-cols):
//   - W_hh slice = 256 KB -> 32 f16x8 B-frags/lane = 128 VGPRs, ALL in
//     registers. No wlds, no spill. LDS = own-half h dbuf + x slab only.
//   - Per step per wave: 32 MFMA (was 64); epilogue 4 gate-sets/lane
//     (was 8) -> transcendental cycles halve.
//   - h exchange: own half via LDS dbuf; partner half via L3-coherent
//     agent-scope atomics on X[buf(s&1)][stripe][half][row][unit] plus a
//     per-wg monotonic step flag. Writer: relaxed sc1 2B stores in the
//     epilogue -> __syncthreads (drains vmcnt => stores at L3) -> tid0
//     release-stores flag=s+1. Reader (step s): relaxed-spin flag>=s,
//     acquire fence, 8x u64 relaxed atomic loads/lane.
//     WAR: we overwrite X[b] at step s+2 only after observing partner
//     flag >= s+2, which orders after partner's step-s+1 reads of X[b].
//     Flags are re-zeroed by K1 every launch (graph replay safe).

typedef _Float16 f16x8 __attribute__((ext_vector_type(8)));
typedef _Float16 f16x4 __attribute__((ext_vector_type(4)));
typedef float    f32x4 __attribute__((ext_vector_type(4)));
typedef unsigned long long u64;

#define B_  256
#define S_  512
#define V_  256
#define E_  128
#define H_  256
#define O_  128

// ws layout (bytes)
#define T_OFF     0u              // T2h: 256*256*4 fp16            = 512 KiB
#define HLAST_OFF (512u << 10)    // hlast: 256*256*4B              = 256 KiB
#define X_OFF     (768u << 10)    // X: 2buf*16*2half*16*128 fp16   = 256 KiB
#define FLAG_OFF  (1024u << 10)   // 32 flags, 128B apart           =   4 KiB

#define SC_AGENT __HIP_MEMORY_SCOPE_AGENT

// ---------------------------------------------------------------- K1: table
// T2h[v][unit] = fp16x4 {i,f,g,o} pre-activations from the embedding path.
// Also re-zeroes the exchange flags each launch (runs before K2 in-stream;
// end-of-kernel flush makes the zeros visible to K2's sc1 reads).
__global__ void build_table(const float* __restrict__ emb,
                            const float* __restrict__ W_ih,
                            const float* __restrict__ b_ih,
                            const float* __restrict__ b_hh,
                            _Float16* __restrict__ T2h,
                            unsigned* __restrict__ flags) {
    const int v   = blockIdx.x;   // vocab id
    const int tid = threadIdx.x;  // 256 threads = hidden unit

    if (blockIdx.x == 0 && tid < 32)
        __hip_atomic_store(&flags[tid * 32], 0u, __ATOMIC_RELAXED, SC_AGENT);

    __shared__ float e[E_];
    if (tid < E_) e[tid] = emb[v * E_ + tid];
    __syncthreads();

    f16x4 tv;
#pragma unroll
    for (int t = 0; t < 4; ++t) {
        const int g = t * 256 + tid;
        const float4* wp = (const float4*)(W_ih + g * E_);
        float acc = 0.f;
#pragma unroll
        for (int i = 0; i < E_ / 4; ++i) {
            float4 w = wp[i];
            acc += w.x * e[4*i] + w.y * e[4*i+1] + w.z * e[4*i+2] + w.w * e[4*i+3];
        }
        tv[t] = (_Float16)(acc + b_ih[g] + b_hh[g]);
    }
    *(f16x4*)(T2h + ((size_t)v * 256 + tid) * 4) = tv;
}

// ------------------------------------------------------------ K2: recurrence
// Pre-act bounds: |W_hh row . h| <= 256*(1/16)*1 = 16 hard; |table| < ~5.
// So sigmoid needs no clamp (exp2 arg < ~60); tanh keeps a +-30 clamp as
// overflow insurance (e^{-2x} overflows only past |x|~44).
__device__ __forceinline__ float sig_fast(float x) {
    float t = __builtin_amdgcn_exp2f(-1.4426950408889634f * x);
    return __builtin_amdgcn_rcpf(1.f + t);
}
__device__ __forceinline__ float tanh_fast(float x) {
    x = fminf(fmaxf(x, -30.f), 30.f);
    float t = __builtin_amdgcn_exp2f(-2.8853900817779268f * x);  // e^{-2x}
    return (1.f - t) * __builtin_amdgcn_rcpf(1.f + t);
}

#define HSTRIDE 136   // fp16 per LDS h row: 128 + 8 pad

__launch_bounds__(512, 2)
__global__ void lstm_persistent(const int* __restrict__ x,
                                const float* __restrict__ W_hh,
                                const _Float16* __restrict__ T2h,
                                float* __restrict__ hlast,
                                unsigned short* __restrict__ Xb,   // fp16 bits
                                unsigned* __restrict__ flags) {
    const int tid    = threadIdx.x;
    const int wv     = tid >> 6;     // wave 0..7
    const int l      = tid & 63;
    const int l15    = l & 15;
    const int quad   = l >> 4;       // 0..3
    const int stripe = blockIdx.x & 15;   // batch rows [stripe*16, +16)
    const int half   = blockIdx.x >> 4;   // hidden half 0/1
    const int uu     = wv * 16 + l15;     // local unit 0..127
    const int u      = half * 128 + uu;   // global hidden unit

    // LDS: own-half h double-buffer (8.5 KB) + this stripe's x slab (33 KB).
    __shared__ __align__(16) _Float16 hbuf[2][16][HSTRIDE];
    __shared__ int xs[16][S_ + 8];

    {   // x[stripe rows][all steps] -> LDS once (kills 4 glb loads/lane/step)
        const int* xg = x + (size_t)stripe * 16 * S_;
        for (int i = tid; i < 16 * S_; i += 512) xs[i >> 9][i & 511] = xg[i];
    }

    // ---- prologue: our W_hh slice -> fp16 MFMA B-frags, ALL in registers.
    // wreg[t][m]: m=0..3 own-half kts (k in [half*128,+128)), m=4..7 partner.
    // col n = l15 <-> unit uu; B[k][n] = W_hh[t*256 + u][k], k=kt*32+quad*8+i.
    // (m is a static index; the runtime `half` only affects the address.)
    f16x8 wreg[4][8];
#pragma unroll
    for (int t = 0; t < 4; ++t) {
        const float* wr = W_hh + (size_t)(t * 256 + u) * H_ + quad * 8;
#pragma unroll
        for (int m = 0; m < 8; ++m) {
            const int ktg = (m < 4) ? (half * 4 + m) : ((1 - half) * 4 + (m - 4));
            const float4* wp = (const float4*)(wr + ktg * 32);
            float4 w0 = wp[0];
            float4 w1 = wp[1];
            wreg[t][m] = (f16x8){
                (_Float16)w0.x, (_Float16)w0.y, (_Float16)w0.z, (_Float16)w0.w,
                (_Float16)w1.x, (_Float16)w1.y, (_Float16)w1.z, (_Float16)w1.w};
        }
    }
    __syncthreads();

    const unsigned* flagP = flags + (stripe * 2 + (1 - half)) * 32;
    unsigned*       flagMe = flags + (stripe * 2 + half) * 32;

    const int row0 = stripe * 16 + quad * 4;   // this lane's 4 C-rows
    float c[4] = {0.f, 0.f, 0.f, 0.f};

    for (int s = 0; s < S_; ++s) {
        // gate-table loads: independent of h -> issue before everything
        f16x4 tvv[4];
#pragma unroll
        for (int r = 0; r < 4; ++r) {
            const int vvr = xs[quad * 4 + r][s];
            tvv[r] = *(const f16x4*)(T2h + ((size_t)vvr * 256 + u) * 4);
        }

        f32x4 acc[4];
#pragma unroll
        for (int t = 0; t < 4; ++t) acc[t] = (f32x4){0.f, 0.f, 0.f, 0.f};

        if (s > 0) {
            // wait for partner h_{s-1} (monotonic step counter)
            while (__hip_atomic_load(flagP, __ATOMIC_RELAXED, SC_AGENT) <
                   (unsigned)s) {}
            __builtin_amdgcn_fence(__ATOMIC_ACQUIRE, "agent");

            // issue partner-half loads first (L3 latency hides under own MFMAs)
            const size_t pb =
                (size_t)(((s - 1) & 1) * 32 + stripe * 2 + (1 - half)) * 2048 +
                (size_t)l15 * 128 + quad * 8;
            u64 pq[4][2];
#pragma unroll
            for (int pk = 0; pk < 4; ++pk) {
                const u64* pp = (const u64*)(Xb + pb + pk * 32);
                pq[pk][0] = __hip_atomic_load(pp,     __ATOMIC_RELAXED, SC_AGENT);
                pq[pk][1] = __hip_atomic_load(pp + 1, __ATOMIC_RELAXED, SC_AGENT);
            }

            // own half from LDS: A row m=l15, k' = j*32 + quad*8 + i
            const _Float16* hb = &hbuf[(s - 1) & 1][0][0] + l15 * HSTRIDE + quad * 8;
#pragma unroll
            for (int j = 0; j < 4; ++j) {
                f16x8 a = *(const f16x8*)(hb + j * 32);
#pragma unroll
                for (int t = 0; t < 4; ++t)
                    acc[t] = __builtin_amdgcn_mfma_f32_16x16x32_f16(
                        a, wreg[t][j], acc[t], 0, 0, 0);
            }
            // partner half from exchanged registers
#pragma unroll
            for (int pk = 0; pk < 4; ++pk) {
                union { u64 q[2]; f16x8 v; } ax;
                ax.q[0] = pq[pk][0];
                ax.q[1] = pq[pk][1];
#pragma unroll
                for (int t = 0; t < 4; ++t)
                    acc[t] = __builtin_amdgcn_mfma_f32_16x16x32_f16(
                        ax.v, wreg[t][4 + pk], acc[t], 0, 0, 0);
            }
        }

        // epilogue: C/D layout col=l15 (unit), row=quad*4+r. acc[t] = gate t.
        const bool last = (s == S_ - 1);
#pragma unroll
        for (int r = 0; r < 4; ++r) {
            float gi = sig_fast (acc[0][r] + (float)tvv[r][0]);
            float gf = sig_fast (acc[1][r] + (float)tvv[r][1]);
            float gg = tanh_fast(acc[2][r] + (float)tvv[r][2]);
            float go = sig_fast (acc[3][r] + (float)tvv[r][3]);
            float cc = gf * c[r] + gi * gg;
            c[r] = cc;
            float hv = go * tanh_fast(cc);
            if (!last) {
                const int ro = quad * 4 + r;
                _Float16 hf = (_Float16)hv;
                hbuf[s & 1][ro][uu] = hf;                    // own-half reuse
                union { _Float16 f; unsigned short b; } cv;  // partner export
                cv.f = hf;
                __hip_atomic_store(
                    Xb + (size_t)((s & 1) * 32 + stripe * 2 + half) * 2048 +
                        ro * 128 + uu,
                    cv.b, __ATOMIC_RELAXED, SC_AGENT);
            } else {
                hlast[(size_t)(row0 + r) * H_ + u] = hv;     // fp32 for head
            }
        }
        // one barrier: hbuf dbuf discipline AND drains the sc1 X stores
        // (syncthreads waits vmcnt(0) per wave => stores are at L3).
        __syncthreads();
        if (!last && tid == 0)
            __hip_atomic_store(flagMe, (unsigned)(s + 1),
                               __ATOMIC_RELEASE, SC_AGENT);
    }
}

// ---------------------------------------------------------------- K3: head
__global__ void out_kernel(const float* __restrict__ hlast,
                           const float* __restrict__ W_out,
                           const float* __restrict__ b_out,
                           float* __restrict__ out) {
    const int b = blockIdx.x;    // 256
    const int o = threadIdx.x;   // 128
    __shared__ float hl[H_];
    hl[o]       = hlast[b * H_ + o];
    hl[o + 128] = hlast[b * H_ + o + 128];
    __syncthreads();
    const float4* wp = (const float4*)(W_out + o * H_);
    float acc = 0.f;
#pragma unroll
    for (int i = 0; i < H_ / 4; ++i) {
        float4 w = wp[i];
        acc += w.x * hl[4*i] + w.y * hl[4*i+1] + w.z * hl[4*i+2] + w.w * hl[4*i+3];
    }
    out[b * O_ + o] = acc + b_out[o];
}

// ----------------------------------------------------------------- launcher
extern "C" void kernel_launch(void* const* d_in, const int* in_sizes, int n_in,
                              void* d_out, int out_size, void* d_ws, size_t ws_size,
                              hipStream_t stream) {
    const int*   x     = (const int*)  d_in[0];
    const float* emb   = (const float*)d_in[1];
    const float* W_ih  = (const float*)d_in[2];
    const float* W_hh  = (const float*)d_in[3];
    const float* b_ih  = (const float*)d_in[4];
    const float* b_hh  = (const float*)d_in[5];
    const float* W_out = (const float*)d_in[6];
    const float* b_out = (const float*)d_in[7];
    float* out = (float*)d_out;

    char* ws = (char*)d_ws;
    _Float16*       T2h   = (_Float16*)(ws + T_OFF);
    float*          hlast = (float*)(ws + HLAST_OFF);
    unsigned short* Xb    = (unsigned short*)(ws + X_OFF);
    unsigned*       flags = (unsigned*)(ws + FLAG_OFF);

    build_table<<<dim3(V_), dim3(256), 0, stream>>>(emb, W_ih, b_ih, b_hh,
                                                    T2h, flags);
    lstm_persistent<<<dim3(32), dim3(512), 0, stream>>>(x, W_hh, T2h, hlast,
                                                        Xb, flags);
    out_kernel<<<dim3(B_), dim3(O_), 0, stream>>>(hlast, W_out, b_out, out);
}

// Round 3
// 1349.277 us; speedup vs baseline: 1.8011x; 1.8011x over previous
//
#include <hip/hip_runtime.h>

// CharNNClassifier: out = (LSTM(emb[x]) last h) @ W_out^T + b_out
// B=256 S=512 V=256 E=128 H=256 4H=1024 O=128, fp32 in/out.
//
// R6 = R5 structure with the HSTRIDE bug fixed + resource budgets made safe.
//  R5 post-mortem: hbuf rows hold 256 units but HSTRIDE was 132 -> every
//  step's h write/read ran into neighboring rows (absmax 0.073). Fix: 264.
//  Also: revert W_hh split to R3-proven 48 reg-frags + kt{0,1} in LDS
//  (R5's 224-VGPR wreg risked spills), drop the x LDS slab (2-deep x
//  register prefetch + 1-deep T2h prefetch instead), bounce in 2 rounds
//  (8 KB). LDS = 128 + 16.5 + 8 = 152.5 KB.
//
//  Structure: 64 wgs x 512 thr, each wg owns 4 batch rows of a 16-row MFMA
//  tile (A rows 4..15 stay zero). W_hh fully replicated per wg. Per step:
//  64 MFMA/wave (same as R3 - CUs were idle anyway), then a per-wave LDS
//  bounce hands the 4 real C-rows (held by quad0) to all 64 lanes so the
//  transcendental epilogue is 2 gate-sets/lane instead of 8. One
//  __syncthreads per step (hbuf double-buffer discipline only).

typedef _Float16 f16x8 __attribute__((ext_vector_type(8)));
typedef _Float16 f16x4 __attribute__((ext_vector_type(4)));
typedef float    f32x4 __attribute__((ext_vector_type(4)));

#define B_  256
#define S_  512
#define V_  256
#define E_  128
#define H_  256
#define O_  128

// ws layout (bytes)
#define T_OFF     0u              // T2h: 256*256*4 fp16 = 512 KiB
#define HLAST_OFF (512u << 10)    // hlast: 256*256*4B   = 256 KiB

// ---------------------------------------------------------------- K1: table
// T2h[v][unit] = fp16x4 {i,f,g,o} pre-activations from the embedding path.
__global__ void build_table(const float* __restrict__ emb,
                            const float* __restrict__ W_ih,
                            const float* __restrict__ b_ih,
                            const float* __restrict__ b_hh,
                            _Float16* __restrict__ T2h) {
    const int v   = blockIdx.x;   // vocab id
    const int tid = threadIdx.x;  // 256 threads = hidden unit

    __shared__ float e[E_];
    if (tid < E_) e[tid] = emb[v * E_ + tid];
    __syncthreads();

    f16x4 tv;
#pragma unroll
    for (int t = 0; t < 4; ++t) {
        const int g = t * 256 + tid;
        const float4* wp = (const float4*)(W_ih + g * E_);
        float acc = 0.f;
#pragma unroll
        for (int i = 0; i < E_ / 4; ++i) {
            float4 w = wp[i];
            acc += w.x * e[4*i] + w.y * e[4*i+1] + w.z * e[4*i+2] + w.w * e[4*i+3];
        }
        tv[t] = (_Float16)(acc + b_ih[g] + b_hh[g]);
    }
    *(f16x4*)(T2h + ((size_t)v * 256 + tid) * 4) = tv;
}

// ------------------------------------------------------------ K2: recurrence
// Pre-act bounds: |W_hh row . h| <= 256*(1/16) = 16 hard; |table| < ~5.
// Sigmoid needs no clamp; tanh keeps a +-30 clamp as overflow insurance.
__device__ __forceinline__ float sig_fast(float x) {
    float t = __builtin_amdgcn_exp2f(-1.4426950408889634f * x);
    return __builtin_amdgcn_rcpf(1.f + t);
}
__device__ __forceinline__ float tanh_fast(float x) {
    x = fminf(fmaxf(x, -30.f), 30.f);
    float t = __builtin_amdgcn_exp2f(-2.8853900817779268f * x);  // e^{-2x}
    return (1.f - t) * __builtin_amdgcn_rcpf(1.f + t);
}

#define HSTRIDE 264   // fp16 per LDS h row: 256 units + 8 pad (R3-proven)

__launch_bounds__(512, 2)
__global__ void lstm_persistent(const int* __restrict__ x,
                                const float* __restrict__ W_hh,
                                const _Float16* __restrict__ T2h,
                                float* __restrict__ hlast) {
    const int tid    = threadIdx.x;
    const int wv     = tid >> 6;     // wave 0..7
    const int l      = tid & 63;
    const int l15    = l & 15;
    const int quad   = l >> 4;       // 0..3
    const int stripe = blockIdx.x;   // batch rows [stripe*4, +4)

    // LDS: 128 KB weights (kt 0..1) + h dbuf (16.5 KB) + bounce (8 KB).
    __shared__ __align__(16) _Float16 wlds[8][8][2][512];   // 128 KiB
    __shared__ __align__(16) _Float16 hbuf[2][16][HSTRIDE]; // 16.5 KiB
    __shared__ __align__(16) float    sc[8][16][4][4];      //   8 KiB

    {   // zero hbuf: rows 4..15 stay zero forever -> pad rows of A read 0
        int* hz = (int*)&hbuf[0][0][0];
        for (int i = tid; i < (int)(sizeof(hbuf) / 4); i += 512) hz[i] = 0;
    }

    // ---- prologue: full W_hh -> fp16 MFMA B-frags (kt 0..1 LDS, 2..7 regs)
    // col n = j*128 + wv*16 + l15; k = kt*32 + quad*8 + i; B[k][n] = W_hh[n][k]
    f16x8 wreg[8][6];
#pragma unroll
    for (int j = 0; j < 8; ++j) {
        const float* wr = W_hh + (size_t)(j * 128 + wv * 16 + l15) * H_ + quad * 8;
#pragma unroll
        for (int kt = 0; kt < 8; ++kt) {
            const float4* wp = (const float4*)(wr + kt * 32);
            float4 w0 = wp[0];
            float4 w1 = wp[1];
            f16x8 f = (f16x8){
                (_Float16)w0.x, (_Float16)w0.y, (_Float16)w0.z, (_Float16)w0.w,
                (_Float16)w1.x, (_Float16)w1.y, (_Float16)w1.z, (_Float16)w1.w};
            if (kt < 2)
                *(f16x8*)&wlds[wv][j][kt][(size_t)l * 8] = f;
            else
                wreg[j][kt - 2] = f;
        }
    }

    // per-lane epilogue mapping: 2 gate-sets.
    const int p     = quad >> 1;               // gate half 0/1
    const int rloc0 = (quad & 1) * 2;          // local rows rloc0, rloc0+1
    const int u     = wv * 16 + l15 + p * 128; // hidden unit
    const int grow0 = stripe * 4 + rloc0;      // global batch rows
    float c2[2] = {0.f, 0.f};

    // bounce addressing: 64 B per (wv,l15), 4 slots, XOR swizzle (2 bits)
    char* scb = (char*)&sc[wv][l15][0][0];
    const int swz = (l15 & 3) << 4;

    // x / T2h software pipeline: x 2 steps ahead, T2h 1 step ahead.
    int xv1[2];
    f16x4 tcv[2], tnx[2];
    {
        int xv0[2];
#pragma unroll
        for (int rr = 0; rr < 2; ++rr) {
            xv0[rr] = x[(size_t)(grow0 + rr) * S_ + 0];
            xv1[rr] = x[(size_t)(grow0 + rr) * S_ + 1];
        }
#pragma unroll
        for (int rr = 0; rr < 2; ++rr)
            tcv[rr] = *(const f16x4*)(T2h + ((size_t)xv0[rr] * 256 + u) * 4);
    }
    __syncthreads();   // wlds + hbuf zeros visible

    for (int s = 0; s < S_; ++s) {
        // issue x load for s+2 and T2h gather for s+1 (resolve next step)
        int xv2[2] = {0, 0};
        if (s + 2 < S_) {
#pragma unroll
            for (int rr = 0; rr < 2; ++rr)
                xv2[rr] = x[(size_t)(grow0 + rr) * S_ + s + 2];
        }
        if (s + 1 < S_) {
#pragma unroll
            for (int rr = 0; rr < 2; ++rr)
                tnx[rr] = *(const f16x4*)(T2h + ((size_t)xv1[rr] * 256 + u) * 4);
        }

        f32x4 acc[8];
#pragma unroll
        for (int j = 0; j < 8; ++j) acc[j] = (f32x4){0.f, 0.f, 0.f, 0.f};

        if (s > 0) {
            // A row m = l15 (rows 4..15 zero), k = kt*32 + quad*8 + i
            const _Float16* hb =
                &hbuf[(s - 1) & 1][0][0] + l15 * HSTRIDE + quad * 8;
#pragma unroll
            for (int kt = 0; kt < 8; ++kt) {
                f16x8 a = *(const f16x8*)(hb + kt * 32);
                if (kt < 2) {
#pragma unroll
                    for (int j = 0; j < 8; ++j) {
                        f16x8 b = *(const f16x8*)&wlds[wv][j][kt][(size_t)l * 8];
                        acc[j] = __builtin_amdgcn_mfma_f32_16x16x32_f16(
                            a, b, acc[j], 0, 0, 0);
                    }
                } else {
#pragma unroll
                    for (int j = 0; j < 8; ++j)
                        acc[j] = __builtin_amdgcn_mfma_f32_16x16x32_f16(
                            a, wreg[j][kt - 2], acc[j], 0, 0, 0);
                }
            }
        }

        // ---- per-wave bounce, 2 rounds (same-wave DS ops are in-order, so
        // round B's writes cannot pass round A's reads; sched_barrier pins
        // the compiler).  acc[j][r] = gates[row r][gate t=j>>1... n-tile j],
        // quad0 holds the real rows 0..3 (C/D row = quad*4 + r).
        float g[2][4];
        // round A: j = 0..3  (reader gates t = 0,1: j = 2t+p <= 3)
        if (quad == 0) {
#pragma unroll
            for (int j = 0; j < 4; ++j)
                *(f32x4*)(scb + ((j * 16) ^ swz)) = acc[j];
        }
        asm volatile("s_waitcnt lgkmcnt(0)" ::: "memory");
        __builtin_amdgcn_sched_barrier(0);
#pragma unroll
        for (int t = 0; t < 2; ++t) {
            const int j = 2 * t + p;
#pragma unroll
            for (int rr = 0; rr < 2; ++rr)
                g[rr][t] = *(const float*)(scb + ((j * 16) ^ swz) +
                                           (rloc0 + rr) * 4);
        }
        __builtin_amdgcn_sched_barrier(0);
        // round B: j = 4..7 reuse the same 4 slots (t = 2,3: j = 2t+p >= 4)
        if (quad == 0) {
#pragma unroll
            for (int j = 4; j < 8; ++j)
                *(f32x4*)(scb + (((j - 4) * 16) ^ swz)) = acc[j];
        }
        asm volatile("s_waitcnt lgkmcnt(0)" ::: "memory");
        __builtin_amdgcn_sched_barrier(0);
#pragma unroll
        for (int t = 2; t < 4; ++t) {
            const int j = 2 * t + p;
#pragma unroll
            for (int rr = 0; rr < 2; ++rr)
                g[rr][t] = *(const float*)(scb + (((j - 4) * 16) ^ swz) +
                                           (rloc0 + rr) * 4);
        }

        // ---- epilogue: 2 gate-sets per lane
        const bool last = (s == S_ - 1);
#pragma unroll
        for (int rr = 0; rr < 2; ++rr) {
            float gi = sig_fast (g[rr][0] + (float)tcv[rr][0]);
            float gf = sig_fast (g[rr][1] + (float)tcv[rr][1]);
            float gg = tanh_fast(g[rr][2] + (float)tcv[rr][2]);
            float go = sig_fast (g[rr][3] + (float)tcv[rr][3]);
            float cc = gf * c2[rr] + gi * gg;
            c2[rr] = cc;
            float hv = go * tanh_fast(cc);
            if (!last) {
                hbuf[s & 1][rloc0 + rr][u] = (_Float16)hv;
            } else {
                hlast[(size_t)(grow0 + rr) * H_ + u] = hv;
            }
        }

        // rotate the prefetch pipeline
#pragma unroll
        for (int rr = 0; rr < 2; ++rr) {
            tcv[rr] = tnx[rr];
            xv1[rr] = xv2[rr];
        }

        // one barrier per step: h_s visible to all waves' A-reads at s+1,
        // and hbuf[(s+1)&1] readers (step s) done before step s+1 overwrites.
        __syncthreads();
    }
}

// ---------------------------------------------------------------- K3: head
__global__ void out_kernel(const float* __restrict__ hlast,
                           const float* __restrict__ W_out,
                           const float* __restrict__ b_out,
                           float* __restrict__ out) {
    const int b = blockIdx.x;    // 256
    const int o = threadIdx.x;   // 128
    __shared__ float hl[H_];
    hl[o]       = hlast[b * H_ + o];
    hl[o + 128] = hlast[b * H_ + o + 128];
    __syncthreads();
    const float4* wp = (const float4*)(W_out + o * H_);
    float acc = 0.f;
#pragma unroll
    for (int i = 0; i < H_ / 4; ++i) {
        float4 w = wp[i];
        acc += w.x * hl[4*i] + w.y * hl[4*i+1] + w.z * hl[4*i+2] + w.w * hl[4*i+3];
    }
    out[b * O_ + o] = acc + b_out[o];
}

// ----------------------------------------------------------------- launcher
extern "C" void kernel_launch(void* const* d_in, const int* in_sizes, int n_in,
                              void* d_out, int out_size, void* d_ws, size_t ws_size,
                              hipStream_t stream) {
    const int*   x     = (const int*)  d_in[0];
    const float* emb   = (const float*)d_in[1];
    const float* W_ih  = (const float*)d_in[2];
    const float* W_hh  = (const float*)d_in[3];
    const float* b_ih  = (const float*)d_in[4];
    const float* b_hh  = (const float*)d_in[5];
    const float* W_out = (const float*)d_in[6];
    const float* b_out = (const float*)d_in[7];
    float* out = (float*)d_out;

    char* ws = (char*)d_ws;
    _Float16* T2h   = (_Float16*)(ws + T_OFF);
    float*    hlast = (float*)(ws + HLAST_OFF);

    build_table<<<dim3(V_), dim3(256), 0, stream>>>(emb, W_ih, b_ih, b_hh, T2h);
    lstm_persistent<<<dim3(64), dim3(512), 0, stream>>>(x, W_hh, T2h, hlast);
    out_kernel<<<dim3(B_), dim3(O_), 0, stream>>>(hlast, W_out, b_out, out);
}

// Round 4
// 1139.367 us; speedup vs baseline: 2.1329x; 1.1842x over previous
//
#include <hip/hip_runtime.h>

// CharNNClassifier: out = (LSTM(emb[x]) last h) @ W_out^T + b_out
// B=256 S=512 V=256 E=128 H=256 4H=1024 O=128, fp32 in/out.
//
// R7 = R6 with the register budget made to FIT (spill elimination).
//  R6 post-mortem: WRITE_SIZE 29.5 MB (vs 1.1 MB in R3) = wreg scratch
//  spill. 192 wreg regs + 32 acc + 2-deep prefetch temps > the 256-reg
//  cap of __launch_bounds__(512,2). The per-step scratch reloads were the
//  ~6000-cyc step time. Also: bounce 128B lane stride = all writers on
//  bank 0 (1.9e7 conflicts).
//
//  R7 changes:
//   - two-pass j-split: acc[4] (16 regs) reused for j 0..3 then j 4..7;
//     bounce after each pass (gates i,f then g,o). A-frags reloaded per
//     pass (8 extra ds_reads, cheap).
//   - prefetch trimmed: x 1 step ahead (2 regs); T2h gather issued at
//     step top, consumed in epilogue (MFMA phase covers latency).
//   - no sched_barrier pins (live-range bloat); only 2x lgkmcnt(0) asm.
//   - bounce rows 80 B apart (20 dwords): writer start-banks spread
//     {0,8,16,24}, ~2-way aliasing (free) instead of 4-way-on-bank-0.
//  Budget: 192 wreg + 16 acc + ~45 misc ~= 253 <= 256.
//  LDS: 128 KB wlds + 16.5 KB hbuf + 10 KB sc = 154.5 KB.

typedef _Float16 f16x8 __attribute__((ext_vector_type(8)));
typedef _Float16 f16x4 __attribute__((ext_vector_type(4)));
typedef float    f32x4 __attribute__((ext_vector_type(4)));

#define B_  256
#define S_  512
#define V_  256
#define E_  128
#define H_  256
#define O_  128

// ws layout (bytes)
#define T_OFF     0u              // T2h: 256*256*4 fp16 = 512 KiB
#define HLAST_OFF (512u << 10)    // hlast: 256*256*4B   = 256 KiB

// ---------------------------------------------------------------- K1: table
// T2h[v][unit] = fp16x4 {i,f,g,o} pre-activations from the embedding path.
__global__ void build_table(const float* __restrict__ emb,
                            const float* __restrict__ W_ih,
                            const float* __restrict__ b_ih,
                            const float* __restrict__ b_hh,
                            _Float16* __restrict__ T2h) {
    const int v   = blockIdx.x;   // vocab id
    const int tid = threadIdx.x;  // 256 threads = hidden unit

    __shared__ float e[E_];
    if (tid < E_) e[tid] = emb[v * E_ + tid];
    __syncthreads();

    f16x4 tv;
#pragma unroll
    for (int t = 0; t < 4; ++t) {
        const int g = t * 256 + tid;
        const float4* wp = (const float4*)(W_ih + g * E_);
        float acc = 0.f;
#pragma unroll
        for (int i = 0; i < E_ / 4; ++i) {
            float4 w = wp[i];
            acc += w.x * e[4*i] + w.y * e[4*i+1] + w.z * e[4*i+2] + w.w * e[4*i+3];
        }
        tv[t] = (_Float16)(acc + b_ih[g] + b_hh[g]);
    }
    *(f16x4*)(T2h + ((size_t)v * 256 + tid) * 4) = tv;
}

// ------------------------------------------------------------ K2: recurrence
// Pre-act bounds: |W_hh row . h| <= 256*(1/16) = 16 hard; |table| < ~5.
// Sigmoid needs no clamp; tanh keeps a +-30 clamp as overflow insurance.
__device__ __forceinline__ float sig_fast(float x) {
    float t = __builtin_amdgcn_exp2f(-1.4426950408889634f * x);
    return __builtin_amdgcn_rcpf(1.f + t);
}
__device__ __forceinline__ float tanh_fast(float x) {
    x = fminf(fmaxf(x, -30.f), 30.f);
    float t = __builtin_amdgcn_exp2f(-2.8853900817779268f * x);  // e^{-2x}
    return (1.f - t) * __builtin_amdgcn_rcpf(1.f + t);
}

#define HSTRIDE 264   // fp16 per LDS h row: 256 units + 8 pad (bank-balanced)

__launch_bounds__(512, 2)
__global__ void lstm_persistent(const int* __restrict__ x,
                                const float* __restrict__ W_hh,
                                const _Float16* __restrict__ T2h,
                                float* __restrict__ hlast) {
    const int tid    = threadIdx.x;
    const int wv     = tid >> 6;     // wave 0..7
    const int l      = tid & 63;
    const int l15    = l & 15;
    const int quad   = l >> 4;       // 0..3
    const int stripe = blockIdx.x;   // batch rows [stripe*4, +4)

    // LDS: 128 KB weights (kt 0..1) + h dbuf (16.5 KB) + bounce (10 KB).
    __shared__ __align__(16) _Float16 wlds[8][8][2][512];   // 128 KiB
    __shared__ __align__(16) _Float16 hbuf[2][16][HSTRIDE]; // 16.5 KiB
    __shared__ __align__(16) float    sc[8][16][20];        //  10 KiB

    {   // zero hbuf: rows 4..15 stay zero forever -> pad rows of A read 0
        int* hz = (int*)&hbuf[0][0][0];
        for (int i = tid; i < (int)(sizeof(hbuf) / 4); i += 512) hz[i] = 0;
    }

    // ---- prologue: full W_hh -> fp16 MFMA B-frags (kt 0..1 LDS, 2..7 regs)
    // col n = j*128 + wv*16 + l15; k = kt*32 + quad*8 + i; B[k][n] = W_hh[n][k]
    f16x8 wreg[8][6];
#pragma unroll
    for (int j = 0; j < 8; ++j) {
        const float* wr = W_hh + (size_t)(j * 128 + wv * 16 + l15) * H_ + quad * 8;
#pragma unroll
        for (int kt = 0; kt < 8; ++kt) {
            const float4* wp = (const float4*)(wr + kt * 32);
            float4 w0 = wp[0];
            float4 w1 = wp[1];
            f16x8 f = (f16x8){
                (_Float16)w0.x, (_Float16)w0.y, (_Float16)w0.z, (_Float16)w0.w,
                (_Float16)w1.x, (_Float16)w1.y, (_Float16)w1.z, (_Float16)w1.w};
            if (kt < 2)
                *(f16x8*)&wlds[wv][j][kt][(size_t)l * 8] = f;
            else
                wreg[j][kt - 2] = f;
        }
    }

    // per-lane epilogue mapping: 2 gate-sets.
    const int p     = quad >> 1;               // gate half 0/1
    const int rloc0 = (quad & 1) * 2;          // local rows rloc0, rloc0+1
    const int u     = wv * 16 + l15 + p * 128; // hidden unit
    const int grow0 = stripe * 4 + rloc0;      // global batch rows
    float c2[2] = {0.f, 0.f};

    // bounce addressing: 80 B per (wv,l15) row, 4 slots, 2-bit XOR swizzle
    char* scb = (char*)&sc[wv][l15][0];
    const int swz = (l15 & 3) << 4;

    // x prefetch: 1 step ahead only.
    int xv[2];
#pragma unroll
    for (int rr = 0; rr < 2; ++rr) xv[rr] = x[(size_t)(grow0 + rr) * S_ + 0];

    __syncthreads();   // wlds + hbuf zeros visible

    for (int s = 0; s < S_; ++s) {
        // T2h gather for THIS step (consumed in epilogue; MFMA covers latency)
        f16x4 tcv[2];
#pragma unroll
        for (int rr = 0; rr < 2; ++rr)
            tcv[rr] = *(const f16x4*)(T2h + ((size_t)xv[rr] * 256 + u) * 4);
        // x for next step
        if (s + 1 < S_) {
#pragma unroll
            for (int rr = 0; rr < 2; ++rr)
                xv[rr] = x[(size_t)(grow0 + rr) * S_ + s + 1];
        }

        float g[2][4];
        // ---- two passes: pass 0 -> j 0..3 (gates i,f), pass 1 -> j 4..7
        // (g,o). acc regs reused across passes; bounce slots reused (same-
        // wave DS pipe is in-order, so pass-1 writes can't pass pass-0
        // reads; asm "memory" clobber orders the compiler's ds ops).
#pragma unroll
        for (int pass = 0; pass < 2; ++pass) {
            f32x4 acc[4];
#pragma unroll
            for (int jj = 0; jj < 4; ++jj) acc[jj] = (f32x4){0.f, 0.f, 0.f, 0.f};

            if (s > 0) {
                // A row m = l15 (rows 4..15 zero), k = kt*32 + quad*8 + i
                const _Float16* hb =
                    &hbuf[(s - 1) & 1][0][0] + l15 * HSTRIDE + quad * 8;
#pragma unroll
                for (int kt = 0; kt < 8; ++kt) {
                    f16x8 a = *(const f16x8*)(hb + kt * 32);
                    if (kt < 2) {
#pragma unroll
                        for (int jj = 0; jj < 4; ++jj) {
                            f16x8 b = *(const f16x8*)
                                &wlds[wv][pass * 4 + jj][kt][(size_t)l * 8];
                            acc[jj] = __builtin_amdgcn_mfma_f32_16x16x32_f16(
                                a, b, acc[jj], 0, 0, 0);
                        }
                    } else {
#pragma unroll
                        for (int jj = 0; jj < 4; ++jj)
                            acc[jj] = __builtin_amdgcn_mfma_f32_16x16x32_f16(
                                a, wreg[pass * 4 + jj][kt - 2], acc[jj], 0, 0, 0);
                    }
                }
            }

            // bounce: quad0 holds the 4 real C-rows (C/D row = quad*4 + r)
            if (quad == 0) {
#pragma unroll
                for (int jj = 0; jj < 4; ++jj)
                    *(f32x4*)(scb + ((jj * 16) ^ swz)) = acc[jj];
            }
            asm volatile("s_waitcnt lgkmcnt(0)" ::: "memory");
#pragma unroll
            for (int t2 = 0; t2 < 2; ++t2) {
                const int jj = 2 * t2 + p;         // slot within this pass
#pragma unroll
                for (int rr = 0; rr < 2; ++rr)
                    g[rr][pass * 2 + t2] = *(const float*)
                        (scb + ((jj * 16) ^ swz) + (rloc0 + rr) * 4);
            }
        }

        // ---- epilogue: 2 gate-sets per lane
        const bool last = (s == S_ - 1);
#pragma unroll
        for (int rr = 0; rr < 2; ++rr) {
            float gi = sig_fast (g[rr][0] + (float)tcv[rr][0]);
            float gf = sig_fast (g[rr][1] + (float)tcv[rr][1]);
            float gg = tanh_fast(g[rr][2] + (float)tcv[rr][2]);
            float go = sig_fast (g[rr][3] + (float)tcv[rr][3]);
            float cc = gf * c2[rr] + gi * gg;
            c2[rr] = cc;
            float hv = go * tanh_fast(cc);
            if (!last) {
                hbuf[s & 1][rloc0 + rr][u] = (_Float16)hv;
            } else {
                hlast[(size_t)(grow0 + rr) * H_ + u] = hv;
            }
        }

        // one barrier per step: h_s visible to all waves' A-reads at s+1,
        // and hbuf[(s+1)&1] readers (step s) done before step s+1 overwrites.
        __syncthreads();
    }
}

// ---------------------------------------------------------------- K3: head
__global__ void out_kernel(const float* __restrict__ hlast,
                           const float* __restrict__ W_out,
                           const float* __restrict__ b_out,
                           float* __restrict__ out) {
    const int b = blockIdx.x;    // 256
    const int o = threadIdx.x;   // 128
    __shared__ float hl[H_];
    hl[o]       = hlast[b * H_ + o];
    hl[o + 128] = hlast[b * H_ + o + 128];
    __syncthreads();
    const float4* wp = (const float4*)(W_out + o * H_);
    float acc = 0.f;
#pragma unroll
    for (int i = 0; i < H_ / 4; ++i) {
        float4 w = wp[i];
        acc += w.x * hl[4*i] + w.y * hl[4*i+1] + w.z * hl[4*i+2] + w.w * hl[4*i+3];
    }
    out[b * O_ + o] = acc + b_out[o];
}

// ----------------------------------------------------------------- launcher
extern "C" void kernel_launch(void* const* d_in, const int* in_sizes, int n_in,
                              void* d_out, int out_size, void* d_ws, size_t ws_size,
                              hipStream_t stream) {
    const int*   x     = (const int*)  d_in[0];
    const float* emb   = (const float*)d_in[1];
    const float* W_ih  = (const float*)d_in[2];
    const float* W_hh  = (const float*)d_in[3];
    const float* b_ih  = (const float*)d_in[4];
    const float* b_hh  = (const float*)d_in[5];
    const float* W_out = (const float*)d_in[6];
    const float* b_out = (const float*)d_in[7];
    float* out = (float*)d_out;

    char* ws = (char*)d_ws;
    _Float16* T2h   = (_Float16*)(ws + T_OFF);
    float*    hlast = (float*)(ws + HLAST_OFF);

    build_table<<<dim3(V_), dim3(256), 0, stream>>>(emb, W_ih, b_ih, b_hh, T2h);
    lstm_persistent<<<dim3(64), dim3(512), 0, stream>>>(x, W_hh, T2h, hlast);
    out_kernel<<<dim3(B_), dim3(O_), 0, stream>>>(hlast, W_out, b_out, out);
}

// Round 5
// 1102.593 us; speedup vs baseline: 2.2041x; 1.0334x over previous
//
#include <hip/hip_runtime.h>

// CharNNClassifier: out = (LSTM(emb[x]) last h) @ W_out^T + b_out
// B=256 S=512 V=256 E=128 H=256 4H=1024 O=128, fp32 in/out.
//
// R8: deliberate W-streaming instead of allocator-spilled wreg.
//  R7 post-mortem: WRITE_SIZE still 27.6 MB = the whole 48-frag wreg
//  spilled again (alloc splits the 256-reg budget 128 VGPR / 128 AGPR and
//  dumps MFMA-operand arrays that don't fit the AGPR half). Every step
//  re-read ~25 MB of W-frags from scratch with compiler-placed waits.
//  W_hh fp16 (512 KB) can't be CU-resident (regfile 512 KB + LDS 160 KB);
//  some slice MUST stream from L2 -> make it explicit and prefetchable:
//   - kt 0..1 -> LDS (128 KB);  kt 2..5 -> wreg[8][4] = 128 VGPRs;
//     kt 6..7 -> streamed per pass from a prepacked fragment buffer Wpk
//     (K1b), 8 coalesced 16B loads/lane/pass issued before the 24
//     resident MFMAs (~500 cyc of cover). Peak regs ~215 < 256: no spill.
//   - zero-A shortcut: A rows 4..15 are structurally zero; lanes l15>=4
//     read a 512B zeroed LDS block (one addr-select) instead of strided
//     hbuf rows. hbuf -> [2][4][264] (4.2 KB), conflicts on A-reads gone.
//  LDS = 128 + 4.2 + 10 (bounce) + 0.5 (zbuf) = 142.7 KB.

typedef _Float16 f16x8 __attribute__((ext_vector_type(8)));
typedef _Float16 f16x4 __attribute__((ext_vector_type(4)));
typedef float    f32x4 __attribute__((ext_vector_type(4)));

#define B_  256
#define S_  512
#define V_  256
#define E_  128
#define H_  256
#define O_  128

// ws layout (bytes)
#define T_OFF     0u              // T2h: 256*256*4 fp16 = 512 KiB
#define HLAST_OFF (512u << 10)    // hlast: 256*256*4B   = 256 KiB
#define WPK_OFF   (768u << 10)    // Wpk: 16*512*16B     = 128 KiB

// ---------------------------------------------------------------- K1: table
// T2h[v][unit] = fp16x4 {i,f,g,o} pre-activations from the embedding path.
__global__ void build_table(const float* __restrict__ emb,
                            const float* __restrict__ W_ih,
                            const float* __restrict__ b_ih,
                            const float* __restrict__ b_hh,
                            _Float16* __restrict__ T2h) {
    const int v   = blockIdx.x;   // vocab id
    const int tid = threadIdx.x;  // 256 threads = hidden unit

    __shared__ float e[E_];
    if (tid < E_) e[tid] = emb[v * E_ + tid];
    __syncthreads();

    f16x4 tv;
#pragma unroll
    for (int t = 0; t < 4; ++t) {
        const int g = t * 256 + tid;
        const float4* wp = (const float4*)(W_ih + g * E_);
        float acc = 0.f;
#pragma unroll
        for (int i = 0; i < E_ / 4; ++i) {
            float4 w = wp[i];
            acc += w.x * e[4*i] + w.y * e[4*i+1] + w.z * e[4*i+2] + w.w * e[4*i+3];
        }
        tv[t] = (_Float16)(acc + b_ih[g] + b_hh[g]);
    }
    *(f16x4*)(T2h + ((size_t)v * 256 + tid) * 4) = tv;
}

// ------------------------------------------------------- K1b: W-frag prepack
// Wpk[blk=ktS*8+j][tid] = the f16x8 B-fragment that thread tid of any wg
// needs for (kt = 6+ktS, j). Lane math mirrors the main kernel's prologue.
__global__ void prepack(const float* __restrict__ W_hh,
                        _Float16* __restrict__ Wpk) {
    const int blk = blockIdx.x;      // 0..15 = ktS*8 + j
    const int ktS = blk >> 3;
    const int j   = blk & 7;
    const int kt  = 6 + ktS;
    const int tid = threadIdx.x;     // 512
    const int wv = tid >> 6, l = tid & 63, l15 = l & 15, quad = l >> 4;
    const int n  = j * 128 + wv * 16 + l15;   // gate column
    const int k0 = kt * 32 + quad * 8;
    const float4* wp = (const float4*)(W_hh + (size_t)n * H_ + k0);
    float4 w0 = wp[0];
    float4 w1 = wp[1];
    f16x8 f = (f16x8){
        (_Float16)w0.x, (_Float16)w0.y, (_Float16)w0.z, (_Float16)w0.w,
        (_Float16)w1.x, (_Float16)w1.y, (_Float16)w1.z, (_Float16)w1.w};
    *(f16x8*)(Wpk + ((size_t)blk * 512 + tid) * 8) = f;
}

// ------------------------------------------------------------ K2: recurrence
// Pre-act bounds: |W_hh row . h| <= 256*(1/16) = 16 hard; |table| < ~5.
// Sigmoid needs no clamp; tanh keeps a +-30 clamp as overflow insurance.
__device__ __forceinline__ float sig_fast(float x) {
    float t = __builtin_amdgcn_exp2f(-1.4426950408889634f * x);
    return __builtin_amdgcn_rcpf(1.f + t);
}
__device__ __forceinline__ float tanh_fast(float x) {
    x = fminf(fmaxf(x, -30.f), 30.f);
    float t = __builtin_amdgcn_exp2f(-2.8853900817779268f * x);  // e^{-2x}
    return (1.f - t) * __builtin_amdgcn_rcpf(1.f + t);
}

#define HSTRIDE 264   // fp16 per LDS h row: 256 units + 8 pad

__launch_bounds__(512, 2)
__global__ void lstm_persistent(const int* __restrict__ x,
                                const float* __restrict__ W_hh,
                                const _Float16* __restrict__ T2h,
                                const _Float16* __restrict__ Wpk,
                                float* __restrict__ hlast) {
    const int tid    = threadIdx.x;
    const int wv     = tid >> 6;     // wave 0..7
    const int l      = tid & 63;
    const int l15    = l & 15;
    const int quad   = l >> 4;       // 0..3
    const int stripe = blockIdx.x;   // batch rows [stripe*4, +4)

    // LDS: 128 KB weights (kt 0..1) + h dbuf (4.2 KB) + bounce (10 KB)
    //      + 512 B zero block for pad rows of A.
    __shared__ __align__(16) _Float16 wlds[8][8][2][512];   // 128 KiB
    __shared__ __align__(16) _Float16 hbuf[2][4][HSTRIDE];  // 4.125 KiB
    __shared__ __align__(16) float    sc[8][16][20];        //  10 KiB
    __shared__ __align__(16) _Float16 zbuf[256];            // 512 B zeros

    if (tid < 128) ((int*)zbuf)[tid] = 0;

    // ---- prologue: kt 0..5 of W_hh -> fp16 B-frags (kt 0..1 LDS, 2..5 reg)
    // col n = j*128 + wv*16 + l15; k = kt*32 + quad*8 + i; B[k][n] = W_hh[n][k]
    f16x8 wreg[8][4];
#pragma unroll
    for (int j = 0; j < 8; ++j) {
        const float* wr = W_hh + (size_t)(j * 128 + wv * 16 + l15) * H_ + quad * 8;
#pragma unroll
        for (int kt = 0; kt < 6; ++kt) {
            const float4* wp = (const float4*)(wr + kt * 32);
            float4 w0 = wp[0];
            float4 w1 = wp[1];
            f16x8 f = (f16x8){
                (_Float16)w0.x, (_Float16)w0.y, (_Float16)w0.z, (_Float16)w0.w,
                (_Float16)w1.x, (_Float16)w1.y, (_Float16)w1.z, (_Float16)w1.w};
            if (kt < 2)
                *(f16x8*)&wlds[wv][j][kt][(size_t)l * 8] = f;
            else
                wreg[j][kt - 2] = f;
        }
    }

    // per-lane epilogue mapping: 2 gate-sets.
    const int p     = quad >> 1;               // gate half 0/1
    const int rloc0 = (quad & 1) * 2;          // local rows rloc0, rloc0+1
    const int u     = wv * 16 + l15 + p * 128; // hidden unit
    const int grow0 = stripe * 4 + rloc0;      // global batch rows
    float c2[2] = {0.f, 0.f};

    // bounce addressing: 80 B per (wv,l15) row, 4 slots, 2-bit XOR swizzle
    char* scb = (char*)&sc[wv][l15][0];
    const int swz = (l15 & 3) << 4;

    // x prefetch: 1 step ahead only.
    int xv[2];
#pragma unroll
    for (int rr = 0; rr < 2; ++rr) xv[rr] = x[(size_t)(grow0 + rr) * S_ + 0];

    __syncthreads();   // wlds + zbuf visible

    for (int s = 0; s < S_; ++s) {
        // T2h gather for THIS step (consumed in epilogue; MFMA covers latency)
        f16x4 tcv[2];
#pragma unroll
        for (int rr = 0; rr < 2; ++rr)
            tcv[rr] = *(const f16x4*)(T2h + ((size_t)xv[rr] * 256 + u) * 4);
        // x for next step
        if (s + 1 < S_) {
#pragma unroll
            for (int rr = 0; rr < 2; ++rr)
                xv[rr] = x[(size_t)(grow0 + rr) * S_ + s + 1];
        }

        // A-frag base: real rows for lanes l15<4, 512B zero block otherwise.
        const _Float16* ha = (l15 < 4)
            ? (&hbuf[(s - 1) & 1][l15][0] + quad * 8)
            : (zbuf + quad * 8);

        float g[2][4];
        // ---- two passes: pass 0 -> j 0..3 (gates i,f), pass 1 -> j 4..7
        // (g,o). acc/bounce-slot reuse across passes (same-wave DS pipe is
        // in-order; asm "memory" clobber orders the compiler's ds ops).
#pragma unroll
        for (int pass = 0; pass < 2; ++pass) {
            // stream kt 6..7 frags for this pass's j's (coalesced 16B/lane;
            // resolved after ~24 resident MFMAs -> L2 latency covered)
            f16x8 wstr[4][2];
#pragma unroll
            for (int jj = 0; jj < 4; ++jj)
#pragma unroll
                for (int ktS = 0; ktS < 2; ++ktS)
                    wstr[jj][ktS] = *(const f16x8*)(
                        Wpk + ((size_t)((ktS * 8 + pass * 4 + jj) * 512 + tid)) * 8);

            f32x4 acc[4];
#pragma unroll
            for (int jj = 0; jj < 4; ++jj) acc[jj] = (f32x4){0.f, 0.f, 0.f, 0.f};

            if (s > 0) {
#pragma unroll
                for (int kt = 0; kt < 8; ++kt) {
                    f16x8 a = *(const f16x8*)(ha + kt * 32);
                    if (kt < 2) {
#pragma unroll
                        for (int jj = 0; jj < 4; ++jj) {
                            f16x8 b = *(const f16x8*)
                                &wlds[wv][pass * 4 + jj][kt][(size_t)l * 8];
                            acc[jj] = __builtin_amdgcn_mfma_f32_16x16x32_f16(
                                a, b, acc[jj], 0, 0, 0);
                        }
                    } else if (kt < 6) {
#pragma unroll
                        for (int jj = 0; jj < 4; ++jj)
                            acc[jj] = __builtin_amdgcn_mfma_f32_16x16x32_f16(
                                a, wreg[pass * 4 + jj][kt - 2], acc[jj], 0, 0, 0);
                    } else {
#pragma unroll
                        for (int jj = 0; jj < 4; ++jj)
                            acc[jj] = __builtin_amdgcn_mfma_f32_16x16x32_f16(
                                a, wstr[jj][kt - 6], acc[jj], 0, 0, 0);
                    }
                }
            }

            // bounce: quad0 holds the 4 real C-rows (C/D row = quad*4 + r)
            if (quad == 0) {
#pragma unroll
                for (int jj = 0; jj < 4; ++jj)
                    *(f32x4*)(scb + ((jj * 16) ^ swz)) = acc[jj];
            }
            asm volatile("s_waitcnt lgkmcnt(0)" ::: "memory");
#pragma unroll
            for (int t2 = 0; t2 < 2; ++t2) {
                const int jj = 2 * t2 + p;         // slot within this pass
#pragma unroll
                for (int rr = 0; rr < 2; ++rr)
                    g[rr][pass * 2 + t2] = *(const float*)
                        (scb + ((jj * 16) ^ swz) + (rloc0 + rr) * 4);
            }
        }

        // ---- epilogue: 2 gate-sets per lane
        const bool last = (s == S_ - 1);
#pragma unroll
        for (int rr = 0; rr < 2; ++rr) {
            float gi = sig_fast (g[rr][0] + (float)tcv[rr][0]);
            float gf = sig_fast (g[rr][1] + (float)tcv[rr][1]);
            float gg = tanh_fast(g[rr][2] + (float)tcv[rr][2]);
            float go = sig_fast (g[rr][3] + (float)tcv[rr][3]);
            float cc = gf * c2[rr] + gi * gg;
            c2[rr] = cc;
            float hv = go * tanh_fast(cc);
            if (!last) {
                hbuf[s & 1][rloc0 + rr][u] = (_Float16)hv;
            } else {
                hlast[(size_t)(grow0 + rr) * H_ + u] = hv;
            }
        }

        // one barrier per step: h_s visible to all waves' A-reads at s+1,
        // and hbuf[(s+1)&1] readers (step s) done before step s+1 overwrites.
        __syncthreads();
    }
}

// ---------------------------------------------------------------- K3: head
__global__ void out_kernel(const float* __restrict__ hlast,
                           const float* __restrict__ W_out,
                           const float* __restrict__ b_out,
                           float* __restrict__ out) {
    const int b = blockIdx.x;    // 256
    const int o = threadIdx.x;   // 128
    __shared__ float hl[H_];
    hl[o]       = hlast[b * H_ + o];
    hl[o + 128] = hlast[b * H_ + o + 128];
    __syncthreads();
    const float4* wp = (const float4*)(W_out + o * H_);
    float acc = 0.f;
#pragma unroll
    for (int i = 0; i < H_ / 4; ++i) {
        float4 w = wp[i];
        acc += w.x * hl[4*i] + w.y * hl[4*i+1] + w.z * hl[4*i+2] + w.w * hl[4*i+3];
    }
    out[b * O_ + o] = acc + b_out[o];
}

// ----------------------------------------------------------------- launcher
extern "C" void kernel_launch(void* const* d_in, const int* in_sizes, int n_in,
                              void* d_out, int out_size, void* d_ws, size_t ws_size,
                              hipStream_t stream) {
    const int*   x     = (const int*)  d_in[0];
    const float* emb   = (const float*)d_in[1];
    const float* W_ih  = (const float*)d_in[2];
    const float* W_hh  = (const float*)d_in[3];
    const float* b_ih  = (const float*)d_in[4];
    const float* b_hh  = (const float*)d_in[5];
    const float* W_out = (const float*)d_in[6];
    const float* b_out = (const float*)d_in[7];
    float* out = (float*)d_out;

    char* ws = (char*)d_ws;
    _Float16* T2h   = (_Float16*)(ws + T_OFF);
    float*    hlast = (float*)(ws + HLAST_OFF);
    _Float16* Wpk   = (_Float16*)(ws + WPK_OFF);

    build_table<<<dim3(V_), dim3(256), 0, stream>>>(emb, W_ih, b_ih, b_hh, T2h);
    prepack<<<dim3(16), dim3(512), 0, stream>>>(W_hh, Wpk);
    lstm_persistent<<<dim3(64), dim3(512), 0, stream>>>(x, W_hh, T2h, Wpk, hlast);
    out_kernel<<<dim3(B_), dim3(O_), 0, stream>>>(hlast, W_out, b_out, out);
}